// Round 4
// baseline (572.672 us; speedup 1.0000x reference)
//
#include <hip/hip_runtime.h>

typedef short s8v __attribute__((ext_vector_type(8)));
typedef float f4v __attribute__((ext_vector_type(4)));

union F8 { int4 i; s8v s; };

__device__ __forceinline__ short f2bf(float f){
  union {float f; unsigned u;} v; v.f = f;
  unsigned r = (v.u + 0x7FFFu + ((v.u >> 16) & 1u)) >> 16;
  return (short)r;
}

#define MFMA(a,b,c) __builtin_amdgcn_mfma_f32_16x16x32_bf16((a),(b),(c),0,0,0)

// ---- workspace layout ----
// [0)      : w_qkv bf16, padded to 304 rows x 96          (58368 B)
// [58368)  : w_proj bf16, 96 x 128 (K padded per head 12->16) (24576 B)
// [82944)  : stats, 16 slices x 192 floats               (12288 B)
// (attention intermediate eliminated: proj fused into attn kernel)
#define WS_W2_OFF   58368
#define WS_ST_OFF   82944
#define N_STAT_SLICES 16

__global__ void prep_kernel(const float* __restrict__ wqkv, const float* __restrict__ wproj,
                            unsigned short* __restrict__ w1, unsigned short* __restrict__ w2p,
                            float* __restrict__ stats){
  int i = blockIdx.x * 256 + threadIdx.x;
  for (int j = i; j < 304*96; j += gridDim.x * 256){
    int row = j / 96, c = j - row * 96;
    float v = (row < 288) ? wqkv[row * 96 + c] : 0.f;
    w1[j] = (unsigned short)f2bf(v);
  }
  for (int j = i; j < 96*128; j += gridDim.x * 256){
    int o = j >> 7, c = j & 127, h = c >> 4, ii = c & 15;
    float v = (ii < 12) ? wproj[o * 96 + h * 12 + ii] : 0.f;
    w2p[j] = (unsigned short)f2bf(v);
  }
  if (i < 192 * N_STAT_SLICES) stats[i] = 0.f;
}

// Fused attention + projection + BN-stats kernel.
// One block per 16x16 window. Single-buffered ks/vs (16.9 KB LDS), 2 barriers/head.
// After each head's final MFMA, the per-head out tile (12 ch x 64 tok per wave) is
// shuffle-transposed (same pattern as bq) into a proj B-fragment half; head PAIRS
// share one K=32 chunk matching w2p's padded layout (cols 12..15 of each head are
// zero weights, so duplicate lanes there are harmless). After the unrolled 8-head
// loop, 6x4x4 MFMAs produce unnormalized fp32 y (written to d_out) + BN stats.
// Head loop fully unrolled: bpair[][] must be statically indexed (reg array).
// Register model (r0-r3 evidence): budget = 512/min_waves; (256,4)=128 is exactly
// the old kernel's usage; +64 bpair regs => (256,3)=170 budget, 12 waves/CU ceiling
// (equal to the old kernel's measured occupancy).
__global__ __launch_bounds__(256,3) void attnproj_kernel(const float* __restrict__ x,
                                                         const unsigned short* __restrict__ w1,
                                                         const unsigned short* __restrict__ w2p,
                                                         float* __restrict__ stats,
                                                         float* __restrict__ y){
  __shared__ short ks[16*264];   // k_norm bf16 [dd][token], rows 12..14 = 0, 15 = ones
  __shared__ short vs[16*264];   // v bf16, same shape/constants
  __shared__ float sld[192];

  const int tid  = threadIdx.x;
  const int lane = tid & 63, wave = tid >> 6;
  const int quad = lane >> 4, col = lane & 15;
  const int wx = blockIdx.x, wy = blockIdx.y, b = blockIdx.z;
  const int h0 = wy * 16, w0 = wx * 16;

  if (tid < 192) sld[tid] = 0.f;   // first use is after the head loop's barriers

  // init constant rows 12..15 (disjoint from per-head scatter rows 0..11; done once)
  for (int i = tid; i < 4*264; i += 256){
    int r = 12 + i / 264, cc = i % 264;
    short v = (r == 15) ? (short)0x3F80 : (short)0;
    ks[r*264 + cc] = v; vs[r*264 + cc] = v;
  }

  // B fragments: X window (K=channel, N=token), loaded once, reused for all heads
  const float* xb = x + ((size_t)b * 96 << 16);
  s8v Bf[4][3];
  #pragma unroll
  for (int jt = 0; jt < 4; ++jt){
    int t0 = wave * 64 + jt * 16;
    const float* px = xb + (size_t)(h0 + (t0 >> 4)) * 256 + (w0 + col);
    #pragma unroll
    for (int kt = 0; kt < 3; ++kt){
      F8 f;
      #pragma unroll
      for (int j = 0; j < 8; ++j){
        int c = kt * 32 + quad * 8 + j;
        f.s[j] = f2bf(px[(size_t)c << 16]);
      }
      Bf[jt][kt] = f.s;
    }
  }

  s8v bpair[4][4];   // proj B-frags: [head pair][jt]; quads 0,1 = even head (k 0..15),
                     // quads 2,3 = odd head (k 16..31)

  #pragma unroll
  for (int h = 0; h < 8; ++h){
    s8v bq[4];   // q-hat B-fragments for the 4 token groups of this wave
    // ---- Q: MFMA + l2norm -> shuffle transpose into bq (registers only) ----
    {
      s8v Aq[3];
      #pragma unroll
      for (int kt = 0; kt < 3; ++kt){
        F8 f; f.i = *(const int4*)(w1 + (h*12 + col) * 96 + kt*32 + quad*8);
        Aq[kt] = f.s;
      }
      #pragma unroll
      for (int jt = 0; jt < 4; ++jt){
        f4v a = {0.f,0.f,0.f,0.f};
        #pragma unroll
        for (int kt = 0; kt < 3; ++kt) a = MFMA(Aq[kt], Bf[jt][kt], a);
        float s = (quad < 3) ? (a[0]*a[0] + a[1]*a[1] + a[2]*a[2] + a[3]*a[3]) : 0.f;
        s += __shfl_xor(s, 16, 64); s += __shfl_xor(s, 32, 64);
        float rq = rsqrtf(s);
        float q0 = a[0]*rq, q1 = a[1]*rq, q2 = a[2]*rq, q3 = a[3]*rq;
        // B[k=quad*8+j][t=col]: k<=11 -> q_norm[k][t]; k==12 -> 1.0; else 0
        int s0 = (quad == 0) ? col        : (32 + col);  // src lane for j=0..3
        int s1 = (quad == 0) ? (16 + col) : (32 + col);  // src lane for j=4..7
        float v0 = __shfl(q0, s0, 64), v1 = __shfl(q1, s0, 64);
        float v2 = __shfl(q2, s0, 64), v3 = __shfl(q3, s0, 64);
        float w4 = __shfl(q0, s1, 64), w5 = __shfl(q1, s1, 64);
        float w6 = __shfl(q2, s1, 64), w7 = __shfl(q3, s1, 64);
        F8 f;
        bool lo = (quad < 2);
        f.s[0] = lo ? f2bf(v0) : (short)0;
        f.s[1] = lo ? f2bf(v1) : (short)0;
        f.s[2] = lo ? f2bf(v2) : (short)0;
        f.s[3] = lo ? f2bf(v3) : (short)0;
        f.s[4] = (quad == 0) ? f2bf(w4) : ((quad == 1) ? (short)0x3F80 : (short)0);
        f.s[5] = (quad == 0) ? f2bf(w5) : (short)0;
        f.s[6] = (quad == 0) ? f2bf(w6) : (short)0;
        f.s[7] = (quad == 0) ? f2bf(w7) : (short)0;
        bq[jt] = f.s;
      }
    }
    __syncthreads();   // barrier 1: previous head's kv reads (and row init) complete
    // ---- K: MFMA + l2norm -> ks scatter ----
    {
      s8v Ak[3];
      #pragma unroll
      for (int kt = 0; kt < 3; ++kt){
        F8 f; f.i = *(const int4*)(w1 + (96 + h*12 + col) * 96 + kt*32 + quad*8);
        Ak[kt] = f.s;
      }
      #pragma unroll
      for (int jt = 0; jt < 4; ++jt){
        f4v a = {0.f,0.f,0.f,0.f};
        #pragma unroll
        for (int kt = 0; kt < 3; ++kt) a = MFMA(Ak[kt], Bf[jt][kt], a);
        float s = (quad < 3) ? (a[0]*a[0] + a[1]*a[1] + a[2]*a[2] + a[3]*a[3]) : 0.f;
        s += __shfl_xor(s, 16, 64); s += __shfl_xor(s, 32, 64);
        float rk = rsqrtf(s);
        if (quad < 3){
          int t = wave*64 + jt*16 + col;
          #pragma unroll
          for (int r = 0; r < 4; ++r) ks[(quad*4 + r)*264 + t] = f2bf(a[r]*rk);
        }
      }
    }
    // ---- V: MFMA -> vs scatter ----
    {
      s8v Av[3];
      #pragma unroll
      for (int kt = 0; kt < 3; ++kt){
        F8 f; f.i = *(const int4*)(w1 + (192 + h*12 + col) * 96 + kt*32 + quad*8);
        Av[kt] = f.s;
      }
      #pragma unroll
      for (int jt = 0; jt < 4; ++jt){
        f4v a = {0.f,0.f,0.f,0.f};
        #pragma unroll
        for (int kt = 0; kt < 3; ++kt) a = MFMA(Av[kt], Bf[jt][kt], a);
        if (quad < 3){
          int t = wave*64 + jt*16 + col;
          #pragma unroll
          for (int r = 0; r < 4; ++r) vs[(quad*4 + r)*264 + t] = f2bf(a[r]);
        }
      }
    }
    __syncthreads();   // barrier 2: ks/vs complete for this head

    // ---- kv (all waves, redundant): kv[m][c] = sum_n ks[m][n] vs[c][n] ----
    f4v kvv = {0.f,0.f,0.f,0.f};
    #pragma unroll
    for (int kk = 0; kk < 8; ++kk){
      F8 a, bv;
      a.i  = *(const int4*)&ks[col*264 + kk*32 + quad*8];
      bv.i = *(const int4*)&vs[col*264 + kk*32 + quad*8];
      kvv = MFMA(a.s, bv.s, kvv);
    }
    // kvv[r] = kv[quad*4+r][col]. Build A-frag A[c'][k]: k<=11 -> kv[k][cc];
    // k==12 -> kv[15][cc] (vsum; for c'==12 it's kv[15][15]=256); k>=13 -> 0.
    F8 fa;
    {
      int cc = (col == 12) ? 15 : col;
      int l0 = ((quad << 1) << 4) | cc;
      int l1 = (((quad << 1) + 1) << 4) | cc;
      float v;
      v = __shfl(kvv[0], l0 & 63, 64); fa.s[0] = f2bf((quad < 2) ? v : 0.f);
      v = __shfl(kvv[1], l0 & 63, 64); fa.s[1] = f2bf((quad < 2) ? v : 0.f);
      v = __shfl(kvv[2], l0 & 63, 64); fa.s[2] = f2bf((quad < 2) ? v : 0.f);
      v = __shfl(kvv[3], l0 & 63, 64); fa.s[3] = f2bf((quad < 2) ? v : 0.f);
      float v0  = __shfl(kvv[0], l1 & 63, 64);
      float v15 = __shfl(kvv[3], 48 | cc, 64);
      fa.s[4] = f2bf((quad == 0) ? v0 : ((quad == 1) ? v15 : 0.f));
      v = __shfl(kvv[1], l1 & 63, 64); fa.s[5] = f2bf((quad == 0) ? v : 0.f);
      v = __shfl(kvv[2], l1 & 63, 64); fa.s[6] = f2bf((quad == 0) ? v : 0.f);
      v = __shfl(kvv[3], l1 & 63, 64); fa.s[7] = f2bf((quad == 0) ? v : 0.f);
    }
    // ---- final: D2 = kvT x qhat; row 12 = denominator (includes the +256) ----
    // out[c'=quad*4+r][t=col] = d2[r]*tl  -> shuffle-transpose into proj B-frag:
    // lane(quad,col) needs out[(quad&1)*8+j][col] for j=0..7 (c' 12..15 feed zero
    // weights in w2p, so duplicate values there are harmless).
    #pragma unroll
    for (int jt = 0; jt < 4; ++jt){
      f4v z = {0.f,0.f,0.f,0.f};
      f4v d2 = MFMA(fa.s, bq[jt], z);
      float dot = __shfl(d2[0], 48 + col, 64);
      float tl = 1.f / dot;
      float o0 = d2[0]*tl, o1 = d2[1]*tl, o2 = d2[2]*tl, o3 = d2[3]*tl;
      int sj0 = ((quad & 1) == 0) ? col        : (32 + col);  // c' = 0..3  / 8..11
      int sj1 = ((quad & 1) == 0) ? (16 + col) : (32 + col);  // c' = 4..7  / (12..15: dead)
      F8 fb;
      fb.s[0] = f2bf(__shfl(o0, sj0, 64));
      fb.s[1] = f2bf(__shfl(o1, sj0, 64));
      fb.s[2] = f2bf(__shfl(o2, sj0, 64));
      fb.s[3] = f2bf(__shfl(o3, sj0, 64));
      fb.s[4] = f2bf(__shfl(o0, sj1, 64));
      fb.s[5] = f2bf(__shfl(o1, sj1, 64));
      fb.s[6] = f2bf(__shfl(o2, sj1, 64));
      fb.s[7] = f2bf(__shfl(o3, sj1, 64));
      if ((quad >> 1) == (h & 1)) bpair[h >> 1][jt] = fb.s;
    }
    // no trailing barrier: barrier 1 of the next head protects the scatter
  }

  // ---- fused proj GEMM: y[o][t] = sum_k w2p[o][k] * outB[k][t], K=128 ----
  // writes unnormalized fp32 y to d_out; BN normalize done in-place by bnfix.
  float* yb = y + ((size_t)(b*96) << 16);
  #pragma unroll
  for (int mt = 0; mt < 6; ++mt){
    s8v Af[4];
    #pragma unroll
    for (int kt = 0; kt < 4; ++kt){
      F8 f; f.i = *(const int4*)(w2p + (mt*16 + col)*128 + kt*32 + quad*8);
      Af[kt] = f.s;
    }
    float rs[4] = {0.f,0.f,0.f,0.f}, rss[4] = {0.f,0.f,0.f,0.f};
    #pragma unroll
    for (int jt = 0; jt < 4; ++jt){
      f4v a = {0.f,0.f,0.f,0.f};
      #pragma unroll
      for (int kt = 0; kt < 4; ++kt) a = MFMA(Af[kt], bpair[kt][jt], a);
      int pix = (h0 + wave*4 + jt) * 256 + (w0 + col);
      #pragma unroll
      for (int r = 0; r < 4; ++r){
        float v = a[r]; rs[r] += v; rss[r] += v*v;
        int ch = mt*16 + quad*4 + r;
        yb[((size_t)ch << 16) + pix] = v;
      }
    }
    #pragma unroll
    for (int r = 0; r < 4; ++r){
      float a1 = rs[r], a2 = rss[r];
      a1 += __shfl_xor(a1, 1, 64); a2 += __shfl_xor(a2, 1, 64);
      a1 += __shfl_xor(a1, 2, 64); a2 += __shfl_xor(a2, 2, 64);
      a1 += __shfl_xor(a1, 4, 64); a2 += __shfl_xor(a2, 4, 64);
      a1 += __shfl_xor(a1, 8, 64); a2 += __shfl_xor(a2, 8, 64);
      if (col == 0){
        int o = mt*16 + quad*4 + r;
        atomicAdd(&sld[o], a1);
        atomicAdd(&sld[96 + o], a2);
      }
    }
  }
  __syncthreads();
  if (tid < 192) atomicAdd(&stats[(blockIdx.x & (N_STAT_SLICES-1))*192 + tid], sld[tid]);
}

// in-place streaming BN apply on d_out: y = y*sc[ch] + sh[ch]
// grid (8, 768): blockIdx.y = b*96+ch row (65536 contiguous floats),
// blockIdx.x = 8 chunks of 8192 floats. No per-iteration div/mod.
__global__ __launch_bounds__(256,8) void bnfix_kernel(const float* __restrict__ stats,
                                                      const float* __restrict__ gamma,
                                                      const float* __restrict__ beta,
                                                      float* __restrict__ y){
  __shared__ float sc[96], sh[96];
  const int tid = threadIdx.x;
  if (tid < 96){
    float s1 = 0.f, s2 = 0.f;
    #pragma unroll
    for (int s = 0; s < N_STAT_SLICES; ++s){ s1 += stats[s*192 + tid]; s2 += stats[s*192 + 96 + tid]; }
    const float invN = 1.f / 524288.f;
    float m  = s1 * invN;
    float var = s2 * invN - m*m;
    float s = gamma[tid] * rsqrtf(var + 1e-5f);
    sc[tid] = s; sh[tid] = beta[tid] - m * s;
  }
  __syncthreads();

  const int row = blockIdx.y;            // b*96 + ch
  const int ch  = row % 96;
  const float scc = sc[ch], shh = sh[ch];
  float* p = y + ((size_t)row << 16) + blockIdx.x * 8192;
  #pragma unroll
  for (int i = 0; i < 8; ++i){
    f4v v = *(f4v*)(p + (i*256 + tid)*4);
    #pragma unroll
    for (int j = 0; j < 4; ++j) v[j] = v[j]*scc + shh;
    *(f4v*)(p + (i*256 + tid)*4) = v;
  }
}

extern "C" void kernel_launch(void* const* d_in, const int* in_sizes, int n_in,
                              void* d_out, int out_size, void* d_ws, size_t ws_size,
                              hipStream_t stream){
  const float* x     = (const float*)d_in[0];
  const float* wqkv  = (const float*)d_in[1];
  const float* wproj = (const float*)d_in[2];
  const float* gamma = (const float*)d_in[3];
  const float* beta  = (const float*)d_in[4];
  char* ws = (char*)d_ws;
  unsigned short* w1  = (unsigned short*)(ws);
  unsigned short* w2p = (unsigned short*)(ws + WS_W2_OFF);
  float* stats = (float*)(ws + WS_ST_OFF);
  float* y = (float*)d_out;

  hipLaunchKernelGGL(prep_kernel, dim3(64), dim3(256), 0, stream, wqkv, wproj, w1, w2p, stats);
  hipLaunchKernelGGL(attnproj_kernel, dim3(16, 16, 8), dim3(256), 0, stream, x, w1, w2p, stats, y);
  hipLaunchKernelGGL(bnfix_kernel, dim3(8, 768), dim3(256), 0, stream, stats, gamma, beta, y);
}